// Round 11
// baseline (618.109 us; speedup 1.0000x reference)
//
#include <hip/hip_runtime.h>

#define N_NODES 50000
#define E_EDGES 800000
#define F 64
#define FE 8
#define H 128
#define MSG_IN 136
#define XPAD 168   // ushorts per sX row (K padded 136->160, +8 spread); 336B
#define HPW 68     // dwords per packed-hidden row (64 data + 4 pad); 272B
#define NXP 136    // ushorts per node sX row (128 data + 8 spread); 272B

typedef short bf16x8 __attribute__((ext_vector_type(8)));
typedef float f32x4 __attribute__((ext_vector_type(4)));

// staging-time scalar conversion (weights, frags)
__device__ __forceinline__ ushort f2bf(float f) {
  uint u = __float_as_uint(f);
  u = (u + 0x7FFFu + ((u >> 16) & 1u)) >> 16;   // RNE
  return (ushort)u;
}
// fast packed conversion: 1 VALU per pair (RNE), gfx950 v_cvt_pk_bf16_f32
__device__ __forceinline__ uint pack2(float lo, float hi) {
  uint r;
  asm("v_cvt_pk_bf16_f32 %0, %1, %2" : "=v"(r) : "v"(lo), "v"(hi));
  return r;
}
__device__ __forceinline__ void atomic_pk_add_bf16(ushort* addr, uint data) {
  asm volatile("global_atomic_pk_add_bf16 %0, %1, off" :: "v"(addr), "v"(data) : "memory");
}

// ---------------------------------------------------------------------------
// One-time f32 -> bf16 feature conversion (iter 0 inputs).
// ---------------------------------------------------------------------------
__global__ __launch_bounds__(256)
void cvt_feats(const float* __restrict__ a, const float* __restrict__ b,
               ushort* __restrict__ oa, ushort* __restrict__ ob) {
  const int n4 = N_NODES * F / 4;
  for (int i = blockIdx.x * blockDim.x + threadIdx.x; i < n4; i += gridDim.x * blockDim.x) {
    const float4 va = ((const float4*)a)[i];
    const float4 vb = ((const float4*)b)[i];
    ((uint2*)oa)[i] = make_uint2(pack2(va.x, va.y), pack2(va.z, va.w));
    ((uint2*)ob)[i] = make_uint2(pack2(vb.x, vb.y), pack2(vb.z, vb.w));
  }
}

// ---------------------------------------------------------------------------
// Counting sort of edges by ev: histogram -> exclusive scan -> scatter perm.
// ---------------------------------------------------------------------------
__global__ __launch_bounds__(256)
void hist_kernel(const int* __restrict__ key, int* __restrict__ cnt) {
  for (int e = blockIdx.x * blockDim.x + threadIdx.x; e < E_EDGES; e += gridDim.x * blockDim.x)
    atomicAdd(&cnt[key[e]], 1);
}

__global__ __launch_bounds__(256)
void scan_kernel(const int* __restrict__ cnt, int* __restrict__ off) {
  __shared__ int part[256];
  const int t = threadIdx.x;
  const int CH = (N_NODES + 255) / 256;   // 196
  int s = 0;
  for (int j = 0; j < CH; ++j) {
    const int idx = t * CH + j;
    if (idx < N_NODES) s += cnt[idx];
  }
  part[t] = s;
  __syncthreads();
  for (int o = 1; o < 256; o <<= 1) {
    int v = 0;
    if (t >= o) v = part[t - o];
    __syncthreads();
    if (t >= o) part[t] += v;
    __syncthreads();
  }
  int run = (t == 0) ? 0 : part[t - 1];
  for (int j = 0; j < CH; ++j) {
    const int idx = t * CH + j;
    if (idx < N_NODES) { off[idx] = run; run += cnt[idx]; }
  }
}

__global__ __launch_bounds__(256)
void scatter_kernel(const int* __restrict__ key, const int* __restrict__ off,
                    int* __restrict__ cnt2, int* __restrict__ perm) {
  for (int e = blockIdx.x * blockDim.x + threadIdx.x; e < E_EDGES; e += gridDim.x * blockDim.x) {
    const int n = key[e];
    const int pos = off[n] + atomicAdd(&cnt2[n], 1);
    perm[pos] = e;
  }
}

// ---------------------------------------------------------------------------
// Edge pass (bf16 MFMA, R9 structure, edges walked in ev-sorted order).
// v-side scatter run-merges consecutive same-node edges in registers
// (b2 folded into v-acc init so each edge contributes its bias once).
// c-side verbatim R9.
// ---------------------------------------------------------------------------
__global__ __launch_bounds__(256, 2)
void edge_pass_mfma(const ushort* __restrict__ vfeat, const ushort* __restrict__ cfeat,
                    const float* __restrict__ efeat,
                    const int* __restrict__ ev, const int* __restrict__ ec,
                    const int* __restrict__ perm,
                    const float* __restrict__ w1, const float* __restrict__ b1,
                    const float* __restrict__ w2, const float* __restrict__ b2,
                    ushort* __restrict__ aggv, ushort* __restrict__ aggc)
{
  __shared__ __align__(16) ushort sX[64 * XPAD];   // 21504 B
  __shared__ __align__(16) uint  sH[128 * HPW];    // 34816 B (v: rows 0-63, c: 64-127)
  __shared__ int sIv[64], sIc[64];                 // 512 B  => 56832 B total

  const int t = threadIdx.x;
  const int wid = t >> 6, l15 = t & 15, hi = (t >> 4) & 3;
  const int eh = wid >> 1, fh = wid & 1;           // layer2: (edge-half, f-half)

  // ---- layer-1 W1 B-frags: col = wid*32 + n*16 + l15; k==136 -> b1 row ----
  bf16x8 bf1[2][5];
  #pragma unroll
  for (int n = 0; n < 2; ++n) {
    const int col = wid * 32 + n * 16 + l15;
    #pragma unroll
    for (int kb = 0; kb < 5; ++kb)
      #pragma unroll
      for (int i = 0; i < 8; ++i) {
        const int kg = kb * 32 + hi * 8 + i;
        float val = 0.f;
        if (kg < MSG_IN) val = w1[kg * H + col];
        else if (kg == MSG_IN) val = b1[col];
        bf1[n][kb][i] = (short)f2bf(val);
      }
  }
  // ---- layer-2 W2 B-frags: packed-hidden slot map on k, adjacent-f map on n
  bf16x8 bf2[2][4];
  #pragma unroll
  for (int fbl = 0; fbl < 2; ++fbl) {
    const int col = fh * 32 + 2 * l15 + fbl;
    #pragma unroll
    for (int kb = 0; kb < 4; ++kb)
      #pragma unroll
      for (int i = 0; i < 8; ++i) {
        const int p = hi * 8 + i;
        const int kl = (p >> 1) | ((p & 1) << 4);
        bf2[fbl][kb][i] = (short)f2bf(w2[(kb * 32 + kl) * F + col]);
      }
  }
  const float bb2[2] = { b2[fh * 32 + 2 * l15], b2[fh * 32 + 2 * l15 + 1] };

  // pad dwords [68,84): col 136 = bf16(1.0) (bias slot), rest zero (once)
  {
    uint* xu = (uint*)sX;
    for (int i = t; i < 64 * 16; i += 256) {
      const int row = i >> 4, u = i & 15;
      xu[row * (XPAD / 2) + 68 + u] = (u == 0) ? 0x00003F80u : 0u;
    }
  }

  const int r = t >> 2, q = t & 3;
  const int g = gridDim.x;
  const int nTiles = E_EDGES / 64;   // 12500 exact
  int tile = blockIdx.x;

  constexpr int perm5[5] = {2, 3, 0, 1, 4};   // c-side: logical [cs|vs|ef]

  // ---- prologue: perm'd idx(t0) + feats(t0) staged; idx(t1) prefetched ----
  int pe = perm[tile * 64 + r];
  int ivC = ev[pe], icC = ec[pe];
  uint4 sv0, sv1, sc0, sc1;
  float4 fe0, fe1;
  {
    const uint4* vp = (const uint4*)(vfeat + (size_t)ivC * F);
    const uint4* cp = (const uint4*)(cfeat + (size_t)icC * F);
    sv0 = vp[q * 2]; sv1 = vp[q * 2 + 1];
    sc0 = cp[q * 2]; sc1 = cp[q * 2 + 1];
    if (q == 0) {
      const float4* ep = (const float4*)(efeat + (size_t)pe * FE);
      fe0 = ep[0]; fe1 = ep[1];
    }
  }
  int peN, ivN, icN;
  {
    const int nt = (tile + g < nTiles) ? tile + g : tile;
    peN = perm[nt * 64 + r];
    ivN = ev[peN]; icN = ec[peN];
  }

  for (; tile < nTiles; tile += g) {
    // ---- (a) sX <- staged regs ----
    {
      uint4* xr4 = (uint4*)((uint*)sX + r * (XPAD / 2));
      xr4[q * 2]     = sv0;
      xr4[q * 2 + 1] = sv1;
      xr4[8 + q * 2]     = sc0;
      xr4[8 + q * 2 + 1] = sc1;
      if (q == 0)
        xr4[16] = make_uint4(pack2(fe0.x, fe0.y), pack2(fe0.z, fe0.w),
                             pack2(fe1.x, fe1.y), pack2(fe1.z, fe1.w));
    }
    __syncthreads();                                    // B1: sX ready
    if (q == 0) { sIv[r] = ivC; sIc[r] = icC; }

    // ---- (b) rotate; issue next tile's feat loads (hide under compute) ----
    ivC = ivN; icC = icN; pe = peN;
    {
      const int t2 = (tile + 2 * g < nTiles) ? tile + 2 * g : tile;
      peN = perm[t2 * 64 + r];
      ivN = ev[peN]; icN = ec[peN];
      const uint4* vp = (const uint4*)(vfeat + (size_t)ivC * F);
      const uint4* cp = (const uint4*)(cfeat + (size_t)icC * F);
      sv0 = vp[q * 2]; sv1 = vp[q * 2 + 1];
      sc0 = cp[q * 2]; sc1 = cp[q * 2 + 1];
      if (q == 0) {
        const float4* ep = (const float4*)(efeat + (size_t)pe * FE);
        fe0 = ep[0]; fe1 = ep[1];
      }
    }

    f32x4 acc[4][2];

    // ---- (c) layer 1, v-side -> sH rows [0,64) ----
    #pragma unroll
    for (int m = 0; m < 4; ++m)
      #pragma unroll
      for (int n = 0; n < 2; ++n) acc[m][n] = (f32x4)(0.f);
    #pragma unroll
    for (int kb = 0; kb < 5; ++kb)
      #pragma unroll
      for (int m = 0; m < 4; ++m) {
        const bf16x8 a = *(const bf16x8*)&sX[(m * 16 + l15) * XPAD + kb * 32 + hi * 8];
        #pragma unroll
        for (int n = 0; n < 2; ++n)
          acc[m][n] = __builtin_amdgcn_mfma_f32_16x16x32_bf16(a, bf1[n][kb], acc[m][n], 0, 0, 0);
      }
    #pragma unroll
    for (int m = 0; m < 4; ++m)
      #pragma unroll
      for (int rr = 0; rr < 4; ++rr) {
        const int e = m * 16 + hi * 4 + rr;
        sH[e * HPW + wid * 16 + l15] =
            pack2(fmaxf(acc[m][0][rr], 0.f), fmaxf(acc[m][1][rr], 0.f));
      }

    // ---- (d) layer 1, c-side (perm'd B-frags) -> sH rows [64,128) ----
    #pragma unroll
    for (int m = 0; m < 4; ++m)
      #pragma unroll
      for (int n = 0; n < 2; ++n) acc[m][n] = (f32x4)(0.f);
    #pragma unroll
    for (int kb = 0; kb < 5; ++kb)
      #pragma unroll
      for (int m = 0; m < 4; ++m) {
        const bf16x8 a = *(const bf16x8*)&sX[(m * 16 + l15) * XPAD + kb * 32 + hi * 8];
        #pragma unroll
        for (int n = 0; n < 2; ++n)
          acc[m][n] = __builtin_amdgcn_mfma_f32_16x16x32_bf16(a, bf1[n][perm5[kb]], acc[m][n], 0, 0, 0);
      }
    #pragma unroll
    for (int m = 0; m < 4; ++m)
      #pragma unroll
      for (int rr = 0; rr < 4; ++rr) {
        const int e = m * 16 + hi * 4 + rr;
        sH[(64 + e) * HPW + wid * 16 + l15] =
            pack2(fmaxf(acc[m][0][rr], 0.f), fmaxf(acc[m][1][rr], 0.f));
      }
    __syncthreads();                                    // B2: all hid ready

    const ushort* sHu = (const ushort*)sH;

    // ---- (e) layer 2, v-side: b2 in acc init; run-merged scatter ----
    {
      f32x4 a2[2][2];
      #pragma unroll
      for (int mm = 0; mm < 2; ++mm) {
        a2[mm][0] = (f32x4)(bb2[0]);
        a2[mm][1] = (f32x4)(bb2[1]);
      }
      #pragma unroll
      for (int kb = 0; kb < 4; ++kb)
        #pragma unroll
        for (int mm = 0; mm < 2; ++mm) {
          const int e = (eh * 2 + mm) * 16 + l15;
          const bf16x8 a = *(const bf16x8*)&sHu[e * (HPW * 2) + kb * 32 + hi * 8];
          a2[mm][0] = __builtin_amdgcn_mfma_f32_16x16x32_bf16(a, bf2[0][kb], a2[mm][0], 0, 0, 0);
          a2[mm][1] = __builtin_amdgcn_mfma_f32_16x16x32_bf16(a, bf2[1][kb], a2[mm][1], 0, 0, 0);
        }
      // run-merge over the 4 consecutive (sorted) edges of this lane-group
      #pragma unroll
      for (int mm = 0; mm < 2; ++mm) {
        const int base = (eh * 2 + mm) * 16 + hi * 4;
        int cur = sIv[base];
        float s0 = a2[mm][0][0], s1 = a2[mm][1][0];
        #pragma unroll
        for (int rr = 1; rr < 4; ++rr) {
          const int id = sIv[base + rr];
          const float v0 = a2[mm][0][rr], v1 = a2[mm][1][rr];
          if (id == cur) { s0 += v0; s1 += v1; }
          else {
            atomic_pk_add_bf16(aggv + (size_t)cur * F + fh * 32 + 2 * l15, pack2(s0, s1));
            cur = id; s0 = v0; s1 = v1;
          }
        }
        atomic_pk_add_bf16(aggv + (size_t)cur * F + fh * 32 + 2 * l15, pack2(s0, s1));
      }
    }

    // ---- (f) layer 2, c-side (verbatim R9: bias post-add, per-edge atomics) ----
    {
      f32x4 a2[2][2];
      #pragma unroll
      for (int mm = 0; mm < 2; ++mm) { a2[mm][0] = (f32x4)(0.f); a2[mm][1] = (f32x4)(0.f); }
      #pragma unroll
      for (int kb = 0; kb < 4; ++kb)
        #pragma unroll
        for (int mm = 0; mm < 2; ++mm) {
          const int e = 64 + (eh * 2 + mm) * 16 + l15;
          const bf16x8 a = *(const bf16x8*)&sHu[e * (HPW * 2) + kb * 32 + hi * 8];
          a2[mm][0] = __builtin_amdgcn_mfma_f32_16x16x32_bf16(a, bf2[0][kb], a2[mm][0], 0, 0, 0);
          a2[mm][1] = __builtin_amdgcn_mfma_f32_16x16x32_bf16(a, bf2[1][kb], a2[mm][1], 0, 0, 0);
        }
      #pragma unroll
      for (int mm = 0; mm < 2; ++mm)
        #pragma unroll
        for (int rr = 0; rr < 4; ++rr) {
          const int idx = sIc[(eh * 2 + mm) * 16 + hi * 4 + rr];
          ushort* dst = aggc + (size_t)idx * F + fh * 32 + 2 * l15;
          atomic_pk_add_bf16(dst, pack2(a2[mm][0][rr] + bb2[0], a2[mm][1][rr] + bb2[1]));
        }
    }
  }
}

// ---------------------------------------------------------------------------
// Node update (R9 verbatim), both sides in one launch; feat & agg bf16.
// Updates feat in place (bf16); writes f32 output on final iteration.
// ---------------------------------------------------------------------------
__global__ __launch_bounds__(256, 2)
void node_update_dual(ushort* __restrict__ vfeat, const ushort* __restrict__ vagg,
                      ushort* __restrict__ cfeat, const ushort* __restrict__ cagg,
                      const float* __restrict__ w1v, const float* __restrict__ b1v,
                      const float* __restrict__ w2v, const float* __restrict__ b2v,
                      const float* __restrict__ w1c, const float* __restrict__ b1c,
                      const float* __restrict__ w2c, const float* __restrict__ b2c,
                      float* __restrict__ outv, float* __restrict__ outc,
                      int writeF32)
{
  __shared__ __align__(16) ushort sX[64 * NXP];
  __shared__ __align__(16) uint  sH[64 * HPW];

  const int half = (N_NODES + 63) / 64;   // 782
  const bool isC = (int)blockIdx.x >= half;
  const int tile = isC ? blockIdx.x - half : blockIdx.x;
  ushort* feat = isC ? cfeat : vfeat;
  const ushort* agg = isC ? cagg : vagg;
  const float* w1 = isC ? w1c : w1v;  const float* b1 = isC ? b1c : b1v;
  const float* w2 = isC ? w2c : w2v;  const float* b2 = isC ? b2c : b2v;
  float* outf = isC ? outc : outv;

  const int t = threadIdx.x;
  const int wid = t >> 6, l15 = t & 15, hi = (t >> 4) & 3;

  bf16x8 bf1[2][4];
  #pragma unroll
  for (int n = 0; n < 2; ++n) {
    const int col = wid * 32 + n * 16 + l15;
    #pragma unroll
    for (int kb = 0; kb < 4; ++kb)
      #pragma unroll
      for (int i = 0; i < 8; ++i)
        bf1[n][kb][i] = (short)f2bf(w1[(kb * 32 + hi * 8 + i) * H + col]);
  }
  bf16x8 bf2[2][2][4];
  #pragma unroll
  for (int gg = 0; gg < 2; ++gg)
    #pragma unroll
    for (int fbl = 0; fbl < 2; ++fbl) {
      const int col = gg * 32 + 2 * l15 + fbl;
      #pragma unroll
      for (int kb = 0; kb < 4; ++kb)
        #pragma unroll
        for (int i = 0; i < 8; ++i) {
          const int p = hi * 8 + i;
          const int kl = (p >> 1) | ((p & 1) << 4);
          bf2[gg][fbl][kb][i] = (short)f2bf(w2[(kb * 32 + kl) * F + col]);
        }
    }
  const float bb1[2] = { b1[wid * 32 + l15], b1[wid * 32 + 16 + l15] };
  float bb2[2][2];
  #pragma unroll
  for (int gg = 0; gg < 2; ++gg) {
    bb2[gg][0] = b2[gg * 32 + 2 * l15];
    bb2[gg][1] = b2[gg * 32 + 2 * l15 + 1];
  }

  const int r = t >> 2, q = t & 3;
  {
    const int node = tile * 64 + r;
    const int nc = node < N_NODES ? node : N_NODES - 1;
    const uint4* fp = (const uint4*)(feat + (size_t)nc * F);
    const uint4* ap = (const uint4*)(agg + (size_t)nc * F);
    uint4* xr4 = (uint4*)&sX[r * NXP];
    xr4[q * 2]     = fp[q * 2];
    xr4[q * 2 + 1] = fp[q * 2 + 1];
    xr4[8 + q * 2]     = ap[q * 2];
    xr4[8 + q * 2 + 1] = ap[q * 2 + 1];
  }
  __syncthreads();

  f32x4 aV[4][2];
  #pragma unroll
  for (int m = 0; m < 4; ++m)
    #pragma unroll
    for (int n = 0; n < 2; ++n) aV[m][n] = (f32x4)(0.f);
  #pragma unroll
  for (int kb = 0; kb < 4; ++kb)
    #pragma unroll
    for (int m = 0; m < 4; ++m) {
      const bf16x8 a = *(const bf16x8*)&sX[(m * 16 + l15) * NXP + kb * 32 + hi * 8];
      #pragma unroll
      for (int n = 0; n < 2; ++n)
        aV[m][n] = __builtin_amdgcn_mfma_f32_16x16x32_bf16(a, bf1[n][kb], aV[m][n], 0, 0, 0);
    }
  #pragma unroll
  for (int m = 0; m < 4; ++m)
    #pragma unroll
    for (int rr = 0; rr < 4; ++rr) {
      const int e = m * 16 + hi * 4 + rr;
      sH[e * HPW + wid * 16 + l15] =
          pack2(fmaxf(aV[m][0][rr] + bb1[0], 0.f), fmaxf(aV[m][1][rr] + bb1[1], 0.f));
    }
  __syncthreads();

  f32x4 a2[2][2];
  #pragma unroll
  for (int gg = 0; gg < 2; ++gg)
    #pragma unroll
    for (int fbl = 0; fbl < 2; ++fbl) a2[gg][fbl] = (f32x4)(0.f);
  const ushort* sHu = (const ushort*)sH;
  #pragma unroll
  for (int kb = 0; kb < 4; ++kb) {
    const int e = wid * 16 + l15;
    const bf16x8 a = *(const bf16x8*)&sHu[e * (HPW * 2) + kb * 32 + hi * 8];
    #pragma unroll
    for (int gg = 0; gg < 2; ++gg)
      #pragma unroll
      for (int fbl = 0; fbl < 2; ++fbl)
        a2[gg][fbl] = __builtin_amdgcn_mfma_f32_16x16x32_bf16(a, bf2[gg][fbl][kb], a2[gg][fbl], 0, 0, 0);
  }
  #pragma unroll
  for (int rr = 0; rr < 4; ++rr) {
    const int node = tile * 64 + wid * 16 + hi * 4 + rr;
    if (node < N_NODES) {
      #pragma unroll
      for (int gg = 0; gg < 2; ++gg) {
        const float o0 = a2[gg][0][rr] + bb2[gg][0];
        const float o1 = a2[gg][1][rr] + bb2[gg][1];
        *(uint*)&feat[(size_t)node * F + gg * 32 + 2 * l15] = pack2(o0, o1);
        if (writeF32) {
          float2 o = make_float2(o0, o1);
          *(float2*)&outf[(size_t)node * F + gg * 32 + 2 * l15] = o;
        }
      }
    }
  }
}

extern "C" void kernel_launch(void* const* d_in, const int* in_sizes, int n_in,
                              void* d_out, int out_size, void* d_ws, size_t ws_size,
                              hipStream_t stream) {
  const float* var_feat  = (const float*)d_in[0];
  const float* cons_feat = (const float*)d_in[1];
  const float* edge_feat = (const float*)d_in[2];
  const int*   ev        = (const int*)d_in[3];
  const int*   ec        = (const int*)d_in[4];
  const float* w_msg1  = (const float*)d_in[5];
  const float* b_msg1  = (const float*)d_in[6];
  const float* w_msg2  = (const float*)d_in[7];
  const float* b_msg2  = (const float*)d_in[8];
  const float* w_vupd1 = (const float*)d_in[9];
  const float* b_vupd1 = (const float*)d_in[10];
  const float* w_vupd2 = (const float*)d_in[11];
  const float* b_vupd2 = (const float*)d_in[12];
  const float* w_cupd1 = (const float*)d_in[13];
  const float* b_cupd1 = (const float*)d_in[14];
  const float* w_cupd2 = (const float*)d_in[15];
  const float* b_cupd2 = (const float*)d_in[16];

  const size_t NF = (size_t)N_NODES * F;
  ushort* aggv = (ushort*)d_ws;          // bf16 agg
  ushort* aggc = aggv + NF;
  ushort* vb   = aggc + NF;              // bf16 features (updated in place)
  ushort* cb   = vb + NF;
  int* cnt  = (int*)(cb + NF);
  int* off  = cnt + N_NODES;
  int* cnt2 = off + N_NODES;
  int* perm = cnt2 + N_NODES;            // E ints
  float* outv = (float*)d_out;
  float* outc = outv + NF;

  cvt_feats<<<512, 256, 0, stream>>>(var_feat, cons_feat, vb, cb);

  // one-time counting sort of edges by ev (reused by both iterations)
  hipMemsetAsync(cnt, 0, 2 * N_NODES * sizeof(int), stream);   // cnt + off
  hipMemsetAsync(cnt2, 0, N_NODES * sizeof(int), stream);
  hist_kernel<<<1024, 256, 0, stream>>>(ev, cnt);
  scan_kernel<<<1, 256, 0, stream>>>(cnt, off);
  scatter_kernel<<<1024, 256, 0, stream>>>(ev, off, cnt2, perm);

  for (int it = 0; it < 2; ++it) {
    hipMemsetAsync(aggv, 0, 2 * NF * sizeof(ushort), stream);

    edge_pass_mfma<<<512, 256, 0, stream>>>(vb, cb, edge_feat, ev, ec, perm,
        w_msg1 + (size_t)it * MSG_IN * H, b_msg1 + (size_t)it * H,
        w_msg2 + (size_t)it * H * F,      b_msg2 + (size_t)it * F,
        aggv, aggc);

    node_update_dual<<<1564, 256, 0, stream>>>(vb, aggv, cb, aggc,
        w_vupd1 + (size_t)it * H * H, b_vupd1 + (size_t)it * H,
        w_vupd2 + (size_t)it * H * F, b_vupd2 + (size_t)it * F,
        w_cupd1 + (size_t)it * H * H, b_cupd1 + (size_t)it * H,
        w_cupd2 + (size_t)it * H * F, b_cupd2 + (size_t)it * F,
        outv, outc, it == 1 ? 1 : 0);
  }
}

// Round 15
// 426.766 us; speedup vs baseline: 1.4484x; 1.4484x over previous
//
#include <hip/hip_runtime.h>

#define N_NODES 50000
#define E_EDGES 800000
#define F 64
#define FE 8
#define H 128
#define MSG_IN 136
#define XPAD 168   // ushorts per sX row (K padded 136->160, +8 spread); 336B, 16B-aligned rows
#define HPW 68     // dwords per packed-hidden row (64 data + 4 pad); 272B
#define NXP 136    // ushorts per node sX row (128 data + 8 spread); 272B

typedef short bf16x8 __attribute__((ext_vector_type(8)));
typedef float f32x4 __attribute__((ext_vector_type(4)));

// staging-time scalar conversion (weights, frags)
__device__ __forceinline__ ushort f2bf(float f) {
  uint u = __float_as_uint(f);
  u = (u + 0x7FFFu + ((u >> 16) & 1u)) >> 16;   // RNE
  return (ushort)u;
}
// fast packed conversion: 1 VALU per pair (RNE), gfx950 v_cvt_pk_bf16_f32
__device__ __forceinline__ uint pack2(float lo, float hi) {
  uint r;
  asm("v_cvt_pk_bf16_f32 %0, %1, %2" : "=v"(r) : "v"(lo), "v"(hi));
  return r;
}
__device__ __forceinline__ void atomic_pk_add_bf16(ushort* addr, uint data) {
  asm volatile("global_atomic_pk_add_bf16 %0, %1, off" :: "v"(addr), "v"(data) : "memory");
}

// ---------------------------------------------------------------------------
// One-time f32 -> bf16 conversions: node feats (both) and edge feats.
// ---------------------------------------------------------------------------
__global__ __launch_bounds__(256)
void cvt_feats(const float* __restrict__ a, const float* __restrict__ b,
               const float* __restrict__ e,
               ushort* __restrict__ oa, ushort* __restrict__ ob,
               ushort* __restrict__ oe) {
  const int n4 = N_NODES * F / 4;
  for (int i = blockIdx.x * blockDim.x + threadIdx.x; i < n4; i += gridDim.x * blockDim.x) {
    const float4 va = ((const float4*)a)[i];
    const float4 vb = ((const float4*)b)[i];
    ((uint2*)oa)[i] = make_uint2(pack2(va.x, va.y), pack2(va.z, va.w));
    ((uint2*)ob)[i] = make_uint2(pack2(vb.x, vb.y), pack2(vb.z, vb.w));
  }
  const int e4 = E_EDGES * FE / 4;
  for (int i = blockIdx.x * blockDim.x + threadIdx.x; i < e4; i += gridDim.x * blockDim.x) {
    const float4 ve = ((const float4*)e)[i];
    ((uint2*)oe)[i] = make_uint2(pack2(ve.x, ve.y), pack2(ve.z, ve.w));
  }
}

// ---------------------------------------------------------------------------
// Edge pass (bf16 MFMA) — R9 structure VERBATIM (2 __syncthreads/tile,
// reg-staged prefetch, zero-init + post-add b2). Only change vs R9: efeat
// arrives pre-converted bf16, so q==0 staging is a raw uint4 copy.
// ---------------------------------------------------------------------------
__global__ __launch_bounds__(256, 2)
void edge_pass_mfma(const ushort* __restrict__ vfeat, const ushort* __restrict__ cfeat,
                    const ushort* __restrict__ efeat,
                    const int* __restrict__ ev, const int* __restrict__ ec,
                    const float* __restrict__ w1, const float* __restrict__ b1,
                    const float* __restrict__ w2, const float* __restrict__ b2,
                    ushort* __restrict__ aggv, ushort* __restrict__ aggc)
{
  __shared__ __align__(16) ushort sX[64 * XPAD];   // 21504 B
  __shared__ __align__(16) uint  sH[128 * HPW];    // 34816 B (v: rows 0-63, c: 64-127)
  __shared__ int sIv[64], sIc[64];                 // 512 B  => 56832 B total

  const int t = threadIdx.x;
  const int wid = t >> 6, l15 = t & 15, hi = (t >> 4) & 3;
  const int eh = wid >> 1, fh = wid & 1;           // layer2: (edge-half, f-half)

  // ---- layer-1 W1 B-frags: col = wid*32 + n*16 + l15; k==136 -> b1 row ----
  bf16x8 bf1[2][5];
  #pragma unroll
  for (int n = 0; n < 2; ++n) {
    const int col = wid * 32 + n * 16 + l15;
    #pragma unroll
    for (int kb = 0; kb < 5; ++kb)
      #pragma unroll
      for (int i = 0; i < 8; ++i) {
        const int kg = kb * 32 + hi * 8 + i;
        float val = 0.f;
        if (kg < MSG_IN) val = w1[kg * H + col];
        else if (kg == MSG_IN) val = b1[col];
        bf1[n][kb][i] = (short)f2bf(val);
      }
  }
  // ---- layer-2 W2 B-frags: packed-hidden slot map on k, adjacent-f map on n
  bf16x8 bf2[2][4];
  #pragma unroll
  for (int fbl = 0; fbl < 2; ++fbl) {
    const int col = fh * 32 + 2 * l15 + fbl;
    #pragma unroll
    for (int kb = 0; kb < 4; ++kb)
      #pragma unroll
      for (int i = 0; i < 8; ++i) {
        const int p = hi * 8 + i;
        const int kl = (p >> 1) | ((p & 1) << 4);
        bf2[fbl][kb][i] = (short)f2bf(w2[(kb * 32 + kl) * F + col]);
      }
  }
  const float bb2[2] = { b2[fh * 32 + 2 * l15], b2[fh * 32 + 2 * l15 + 1] };

  // pad dwords [68,84): col 136 = bf16(1.0) (bias slot), rest zero (once)
  {
    uint* xu = (uint*)sX;
    for (int i = t; i < 64 * 16; i += 256) {
      const int row = i >> 4, u = i & 15;
      xu[row * (XPAD / 2) + 68 + u] = (u == 0) ? 0x00003F80u : 0u;
    }
  }

  const int r = t >> 2, q = t & 3;
  const int g = gridDim.x;
  const int nTiles = E_EDGES / 64;   // 12500 exact
  int tile = blockIdx.x;

  constexpr int perm[5] = {2, 3, 0, 1, 4};   // c-side: logical [cs|vs|ef]

  // ---- prologue: idx(t0) + feats(t0) staged in regs; idx(t1) prefetched ----
  int ivC = ev[tile * 64 + r], icC = ec[tile * 64 + r];
  uint4 sv0, sv1, sc0, sc1, se0;
  {
    const uint4* vp = (const uint4*)(vfeat + (size_t)ivC * F);
    const uint4* cp = (const uint4*)(cfeat + (size_t)icC * F);
    sv0 = vp[q * 2]; sv1 = vp[q * 2 + 1];
    sc0 = cp[q * 2]; sc1 = cp[q * 2 + 1];
    if (q == 0)
      se0 = *(const uint4*)(efeat + (size_t)(tile * 64 + r) * FE);
  }
  int ivN, icN;
  {
    const int nt = (tile + g < nTiles) ? tile + g : tile;
    ivN = ev[nt * 64 + r]; icN = ec[nt * 64 + r];
  }

  for (; tile < nTiles; tile += g) {
    // ---- (a) sX <- staged regs (loads long since landed) ----
    {
      uint4* xr4 = (uint4*)((uint*)sX + r * (XPAD / 2));
      xr4[q * 2]     = sv0;
      xr4[q * 2 + 1] = sv1;
      xr4[8 + q * 2]     = sc0;
      xr4[8 + q * 2 + 1] = sc1;
      if (q == 0) xr4[16] = se0;
    }
    __syncthreads();                                    // B1: sX ready
    if (q == 0) { sIv[r] = ivC; sIc[r] = icC; }

    // ---- (b) rotate idx; ISSUE next tile's feat loads (hide under compute)
    ivC = ivN; icC = icN;
    {
      const int t2 = (tile + 2 * g < nTiles) ? tile + 2 * g : tile;
      ivN = ev[t2 * 64 + r]; icN = ec[t2 * 64 + r];
      const uint4* vp = (const uint4*)(vfeat + (size_t)ivC * F);
      const uint4* cp = (const uint4*)(cfeat + (size_t)icC * F);
      sv0 = vp[q * 2]; sv1 = vp[q * 2 + 1];
      sc0 = cp[q * 2]; sc1 = cp[q * 2 + 1];
      if (q == 0) {
        const int en = ((tile + g < nTiles) ? tile + g : tile) * 64 + r;
        se0 = *(const uint4*)(efeat + (size_t)en * FE);
      }
    }

    f32x4 acc[4][2];

    // ---- (c) layer 1, v-side -> sH rows [0,64) ----
    #pragma unroll
    for (int m = 0; m < 4; ++m)
      #pragma unroll
      for (int n = 0; n < 2; ++n) acc[m][n] = (f32x4)(0.f);
    #pragma unroll
    for (int kb = 0; kb < 5; ++kb)
      #pragma unroll
      for (int m = 0; m < 4; ++m) {
        const bf16x8 a = *(const bf16x8*)&sX[(m * 16 + l15) * XPAD + kb * 32 + hi * 8];
        #pragma unroll
        for (int n = 0; n < 2; ++n)
          acc[m][n] = __builtin_amdgcn_mfma_f32_16x16x32_bf16(a, bf1[n][kb], acc[m][n], 0, 0, 0);
      }
    #pragma unroll
    for (int m = 0; m < 4; ++m)
      #pragma unroll
      for (int rr = 0; rr < 4; ++rr) {
        const int e = m * 16 + hi * 4 + rr;
        sH[e * HPW + wid * 16 + l15] =
            pack2(fmaxf(acc[m][0][rr], 0.f), fmaxf(acc[m][1][rr], 0.f));
      }

    // ---- (d) layer 1, c-side (perm'd B-frags) -> sH rows [64,128) ----
    #pragma unroll
    for (int m = 0; m < 4; ++m)
      #pragma unroll
      for (int n = 0; n < 2; ++n) acc[m][n] = (f32x4)(0.f);
    #pragma unroll
    for (int kb = 0; kb < 5; ++kb)
      #pragma unroll
      for (int m = 0; m < 4; ++m) {
        const bf16x8 a = *(const bf16x8*)&sX[(m * 16 + l15) * XPAD + kb * 32 + hi * 8];
        #pragma unroll
        for (int n = 0; n < 2; ++n)
          acc[m][n] = __builtin_amdgcn_mfma_f32_16x16x32_bf16(a, bf1[n][perm[kb]], acc[m][n], 0, 0, 0);
      }
    #pragma unroll
    for (int m = 0; m < 4; ++m)
      #pragma unroll
      for (int rr = 0; rr < 4; ++rr) {
        const int e = m * 16 + hi * 4 + rr;
        sH[(64 + e) * HPW + wid * 16 + l15] =
            pack2(fmaxf(acc[m][0][rr], 0.f), fmaxf(acc[m][1][rr], 0.f));
      }
    __syncthreads();                                    // B2: all hid ready

    // ---- (e) layer 2, v-side then c-side; atomics (zero-init + post-add b2)
    const ushort* sHu = (const ushort*)sH;
    #pragma unroll
    for (int side = 0; side < 2; ++side) {
      f32x4 a2[2][2];
      #pragma unroll
      for (int mm = 0; mm < 2; ++mm) { a2[mm][0] = (f32x4)(0.f); a2[mm][1] = (f32x4)(0.f); }
      #pragma unroll
      for (int kb = 0; kb < 4; ++kb)
        #pragma unroll
        for (int mm = 0; mm < 2; ++mm) {
          const int e = side * 64 + (eh * 2 + mm) * 16 + l15;
          const bf16x8 a = *(const bf16x8*)&sHu[e * (HPW * 2) + kb * 32 + hi * 8];
          a2[mm][0] = __builtin_amdgcn_mfma_f32_16x16x32_bf16(a, bf2[0][kb], a2[mm][0], 0, 0, 0);
          a2[mm][1] = __builtin_amdgcn_mfma_f32_16x16x32_bf16(a, bf2[1][kb], a2[mm][1], 0, 0, 0);
        }
      ushort* agg = side ? aggc : aggv;
      const int* sI = side ? sIc : sIv;
      #pragma unroll
      for (int mm = 0; mm < 2; ++mm)
        #pragma unroll
        for (int rr = 0; rr < 4; ++rr) {
          const int idx = sI[(eh * 2 + mm) * 16 + hi * 4 + rr];
          ushort* dst = agg + (size_t)idx * F + fh * 32 + 2 * l15;
          atomic_pk_add_bf16(dst, pack2(a2[mm][0][rr] + bb2[0], a2[mm][1][rr] + bb2[1]));
        }
    }
  }
}

// ---------------------------------------------------------------------------
// Node update — R9 VERBATIM (zero-init + post-add b2). Both sides, one launch;
// feat & agg bf16 raw staging; updates feat in place; f32 out on final iter.
// ---------------------------------------------------------------------------
__global__ __launch_bounds__(256, 2)
void node_update_dual(ushort* __restrict__ vfeat, const ushort* __restrict__ vagg,
                      ushort* __restrict__ cfeat, const ushort* __restrict__ cagg,
                      const float* __restrict__ w1v, const float* __restrict__ b1v,
                      const float* __restrict__ w2v, const float* __restrict__ b2v,
                      const float* __restrict__ w1c, const float* __restrict__ b1c,
                      const float* __restrict__ w2c, const float* __restrict__ b2c,
                      float* __restrict__ outv, float* __restrict__ outc,
                      int writeF32)
{
  __shared__ __align__(16) ushort sX[64 * NXP];
  __shared__ __align__(16) uint  sH[64 * HPW];

  const int half = (N_NODES + 63) / 64;   // 782
  const bool isC = (int)blockIdx.x >= half;
  const int tile = isC ? blockIdx.x - half : blockIdx.x;
  ushort* feat = isC ? cfeat : vfeat;
  const ushort* agg = isC ? cagg : vagg;
  const float* w1 = isC ? w1c : w1v;  const float* b1 = isC ? b1c : b1v;
  const float* w2 = isC ? w2c : w2v;  const float* b2 = isC ? b2c : b2v;
  float* outf = isC ? outc : outv;

  const int t = threadIdx.x;
  const int wid = t >> 6, l15 = t & 15, hi = (t >> 4) & 3;

  bf16x8 bf1[2][4];
  #pragma unroll
  for (int n = 0; n < 2; ++n) {
    const int col = wid * 32 + n * 16 + l15;
    #pragma unroll
    for (int kb = 0; kb < 4; ++kb)
      #pragma unroll
      for (int i = 0; i < 8; ++i)
        bf1[n][kb][i] = (short)f2bf(w1[(kb * 32 + hi * 8 + i) * H + col]);
  }
  bf16x8 bf2[2][2][4];
  #pragma unroll
  for (int gg = 0; gg < 2; ++gg)
    #pragma unroll
    for (int fbl = 0; fbl < 2; ++fbl) {
      const int col = gg * 32 + 2 * l15 + fbl;
      #pragma unroll
      for (int kb = 0; kb < 4; ++kb)
        #pragma unroll
        for (int i = 0; i < 8; ++i) {
          const int p = hi * 8 + i;
          const int kl = (p >> 1) | ((p & 1) << 4);
          bf2[gg][fbl][kb][i] = (short)f2bf(w2[(kb * 32 + kl) * F + col]);
        }
    }
  const float bb1[2] = { b1[wid * 32 + l15], b1[wid * 32 + 16 + l15] };
  float bb2[2][2];
  #pragma unroll
  for (int gg = 0; gg < 2; ++gg) {
    bb2[gg][0] = b2[gg * 32 + 2 * l15];
    bb2[gg][1] = b2[gg * 32 + 2 * l15 + 1];
  }

  const int r = t >> 2, q = t & 3;
  {
    const int node = tile * 64 + r;
    const int nc = node < N_NODES ? node : N_NODES - 1;
    const uint4* fp = (const uint4*)(feat + (size_t)nc * F);
    const uint4* ap = (const uint4*)(agg + (size_t)nc * F);
    uint4* xr4 = (uint4*)&sX[r * NXP];
    xr4[q * 2]     = fp[q * 2];
    xr4[q * 2 + 1] = fp[q * 2 + 1];
    xr4[8 + q * 2]     = ap[q * 2];
    xr4[8 + q * 2 + 1] = ap[q * 2 + 1];
  }
  __syncthreads();

  f32x4 aV[4][2];
  #pragma unroll
  for (int m = 0; m < 4; ++m)
    #pragma unroll
    for (int n = 0; n < 2; ++n) aV[m][n] = (f32x4)(0.f);
  #pragma unroll
  for (int kb = 0; kb < 4; ++kb)
    #pragma unroll
    for (int m = 0; m < 4; ++m) {
      const bf16x8 a = *(const bf16x8*)&sX[(m * 16 + l15) * NXP + kb * 32 + hi * 8];
      #pragma unroll
      for (int n = 0; n < 2; ++n)
        aV[m][n] = __builtin_amdgcn_mfma_f32_16x16x32_bf16(a, bf1[n][kb], aV[m][n], 0, 0, 0);
    }
  #pragma unroll
  for (int m = 0; m < 4; ++m)
    #pragma unroll
    for (int rr = 0; rr < 4; ++rr) {
      const int e = m * 16 + hi * 4 + rr;
      sH[e * HPW + wid * 16 + l15] =
          pack2(fmaxf(aV[m][0][rr] + bb1[0], 0.f), fmaxf(aV[m][1][rr] + bb1[1], 0.f));
    }
  __syncthreads();

  f32x4 a2[2][2];
  #pragma unroll
  for (int gg = 0; gg < 2; ++gg)
    #pragma unroll
    for (int fbl = 0; fbl < 2; ++fbl) a2[gg][fbl] = (f32x4)(0.f);
  const ushort* sHu = (const ushort*)sH;
  #pragma unroll
  for (int kb = 0; kb < 4; ++kb) {
    const int e = wid * 16 + l15;
    const bf16x8 a = *(const bf16x8*)&sHu[e * (HPW * 2) + kb * 32 + hi * 8];
    #pragma unroll
    for (int gg = 0; gg < 2; ++gg)
      #pragma unroll
      for (int fbl = 0; fbl < 2; ++fbl)
        a2[gg][fbl] = __builtin_amdgcn_mfma_f32_16x16x32_bf16(a, bf2[gg][fbl][kb], a2[gg][fbl], 0, 0, 0);
  }
  #pragma unroll
  for (int rr = 0; rr < 4; ++rr) {
    const int node = tile * 64 + wid * 16 + hi * 4 + rr;
    if (node < N_NODES) {
      #pragma unroll
      for (int gg = 0; gg < 2; ++gg) {
        const float o0 = a2[gg][0][rr] + bb2[gg][0];
        const float o1 = a2[gg][1][rr] + bb2[gg][1];
        *(uint*)&feat[(size_t)node * F + gg * 32 + 2 * l15] = pack2(o0, o1);
        if (writeF32) {
          float2 o = make_float2(o0, o1);
          *(float2*)&outf[(size_t)node * F + gg * 32 + 2 * l15] = o;
        }
      }
    }
  }
}

extern "C" void kernel_launch(void* const* d_in, const int* in_sizes, int n_in,
                              void* d_out, int out_size, void* d_ws, size_t ws_size,
                              hipStream_t stream) {
  const float* var_feat  = (const float*)d_in[0];
  const float* cons_feat = (const float*)d_in[1];
  const float* edge_feat = (const float*)d_in[2];
  const int*   ev        = (const int*)d_in[3];
  const int*   ec        = (const int*)d_in[4];
  const float* w_msg1  = (const float*)d_in[5];
  const float* b_msg1  = (const float*)d_in[6];
  const float* w_msg2  = (const float*)d_in[7];
  const float* b_msg2  = (const float*)d_in[8];
  const float* w_vupd1 = (const float*)d_in[9];
  const float* b_vupd1 = (const float*)d_in[10];
  const float* w_vupd2 = (const float*)d_in[11];
  const float* b_vupd2 = (const float*)d_in[12];
  const float* w_cupd1 = (const float*)d_in[13];
  const float* b_cupd1 = (const float*)d_in[14];
  const float* w_cupd2 = (const float*)d_in[15];
  const float* b_cupd2 = (const float*)d_in[16];

  const size_t NF = (size_t)N_NODES * F;
  ushort* aggv = (ushort*)d_ws;          // bf16 agg
  ushort* aggc = aggv + NF;
  ushort* vb   = aggc + NF;              // bf16 features (updated in place)
  ushort* cb   = vb + NF;
  ushort* eb   = cb + NF;                // bf16 edge features
  float* outv = (float*)d_out;
  float* outc = outv + NF;

  cvt_feats<<<1024, 256, 0, stream>>>(var_feat, cons_feat, edge_feat, vb, cb, eb);

  for (int it = 0; it < 2; ++it) {
    hipMemsetAsync(aggv, 0, 2 * NF * sizeof(ushort), stream);

    edge_pass_mfma<<<512, 256, 0, stream>>>(vb, cb, eb, ev, ec,
        w_msg1 + (size_t)it * MSG_IN * H, b_msg1 + (size_t)it * H,
        w_msg2 + (size_t)it * H * F,      b_msg2 + (size_t)it * F,
        aggv, aggc);

    node_update_dual<<<1564, 256, 0, stream>>>(vb, aggv, cb, aggc,
        w_vupd1 + (size_t)it * H * H, b_vupd1 + (size_t)it * H,
        w_vupd2 + (size_t)it * H * F, b_vupd2 + (size_t)it * F,
        w_cupd1 + (size_t)it * H * H, b_cupd1 + (size_t)it * H,
        w_cupd2 + (size_t)it * H * F, b_cupd2 + (size_t)it * F,
        outv, outc, it == 1 ? 1 : 0);
  }
}